// Round 18
// baseline (268.817 us; speedup 1.0000x reference)
//
#include <hip/hip_runtime.h>

// GCNConv (self-loops, symmetric norm) + bias + PReLU.
// out[d] = prelu( dis[d] * ( sum_{e: dst=d} hs[src_e] + hs[d] ) + b )
// hs = bf16( (x @ W) * dis[row] ) via MFMA; dis = rsqrt(deg+1).
// CSR build via two-level binned counting sort (coalesced writes, few atomics).
// Gather: 2 edges per wave (32 lanes x 8B each), cross-half shfl reduce.

constexpr int N_NODES = 100000;
constexpr int N_EDGES = 1600000;
constexpr int C  = 128;
constexpr int BM = 32;                        // GEMM row tile
constexpr int NBUCK  = (N_NODES + 127) >> 7;  // 782 coarse buckets (128 nodes each)
constexpr int BCHUNK = 8192;                  // edges per block in phase A
constexpr int ABLKS  = (N_EDGES + BCHUNK - 1) / BCHUNK;   // 196
constexpr int BCAP   = 3072;                  // max edges per bucket (mean 2048, sigma 45)

using f32x4 = __attribute__((ext_vector_type(4))) float;
using s16x8 = __attribute__((ext_vector_type(8))) short;   // 8 bf16 = 4 VGPRs

// round-to-nearest-even fp32 -> bf16
__device__ __forceinline__ unsigned short f2bf(float f) {
    unsigned int u = __float_as_uint(f);
    u += 0x7fffu + ((u >> 16) & 1u);
    return (unsigned short)(u >> 16);
}

__global__ __launch_bounds__(1024) void k_zerob(int* __restrict__ bhist) {
    int t = threadIdx.x;
    if (t < NBUCK) bhist[t] = 0;
}

// coarse histogram: one LDS hist per block, one global atomic per (block,bucket)
__global__ __launch_bounds__(256) void k_bhist(const int* __restrict__ dst,
                                               int* __restrict__ bhist) {
    __shared__ int h[NBUCK];
    for (int i = threadIdx.x; i < NBUCK; i += 256) h[i] = 0;
    __syncthreads();
    const int beg = blockIdx.x * BCHUNK;
    const int end = min(beg + BCHUNK, N_EDGES);
    for (int e = beg + threadIdx.x; e < end; e += 256)
        atomicAdd(&h[dst[e] >> 7], 1);
    __syncthreads();
    for (int i = threadIdx.x; i < NBUCK; i += 256)
        if (h[i]) atomicAdd(&bhist[i], h[i]);
}

// exclusive scan of bucket totals -> bbase (and init gcur)
__global__ __launch_bounds__(1024) void k_bscan(const int* __restrict__ bhist,
                                                int* __restrict__ bbase,
                                                int* __restrict__ gcur) {
    __shared__ int s[1024];
    int t = threadIdx.x;
    int v = (t < NBUCK) ? bhist[t] : 0;
    s[t] = v;
    __syncthreads();
#pragma unroll
    for (int off = 1; off < 1024; off <<= 1) {
        int u = (t >= off) ? s[t - off] : 0;
        __syncthreads();
        s[t] += u;
        __syncthreads();
    }
    if (t < NBUCK) { int b = s[t] - v; bbase[t] = b; gcur[t] = b; }
    if (t == 0) bbase[NBUCK] = N_EDGES;
}

// scatter packed (src<<7 | dst&127) into bucket regions; block-private runs
__global__ __launch_bounds__(256) void k_binscatter(const int* __restrict__ src,
                                                    const int* __restrict__ dst,
                                                    int* __restrict__ gcur,
                                                    unsigned int* __restrict__ pairs) {
    __shared__ int h[NBUCK];
    __shared__ int off[NBUCK];
    for (int i = threadIdx.x; i < NBUCK; i += 256) h[i] = 0;
    __syncthreads();
    const int beg = blockIdx.x * BCHUNK;
    const int end = min(beg + BCHUNK, N_EDGES);
    for (int e = beg + threadIdx.x; e < end; e += 256)
        atomicAdd(&h[dst[e] >> 7], 1);
    __syncthreads();
    for (int i = threadIdx.x; i < NBUCK; i += 256)
        off[i] = h[i] ? atomicAdd(&gcur[i], h[i]) : 0;
    __syncthreads();
    for (int e = beg + threadIdx.x; e < end; e += 256) {
        int d = dst[e];
        int bk = d >> 7;
        int pos = atomicAdd(&off[bk], 1);
        pairs[pos] = ((unsigned int)src[e] << 7) | (unsigned int)(d & 127);
    }
}

// per-bucket fine sort in LDS; emits rowptr, dis, and coalesced adj
__global__ __launch_bounds__(256) void k_bucket(const int* __restrict__ bbase,
                                                const unsigned int* __restrict__ pairs,
                                                int* __restrict__ rowptr,
                                                float* __restrict__ dis,
                                                int* __restrict__ adj) {
    __shared__ int h[128];
    __shared__ int excl[128];
    __shared__ int adjl[BCAP];
    const int b = blockIdx.x;
    const int beg = bbase[b], end = bbase[b + 1];
    const int n = end - beg;
    const int t = threadIdx.x;
    if (t < 128) h[t] = 0;
    __syncthreads();
    for (int i = beg + t; i < end; i += 256)
        atomicAdd(&h[pairs[i] & 127u], 1);
    __syncthreads();
    if (t == 0) {
        int acc = 0;
#pragma unroll
        for (int l = 0; l < 128; ++l) { excl[l] = acc; acc += h[l]; }
    }
    __syncthreads();
    if (t < 128) {
        int node = b * 128 + t;
        if (node < N_NODES) {
            rowptr[node] = beg + excl[t];
            dis[node] = rsqrtf((float)(h[t] + 1));
        }
        h[t] = excl[t];    // reuse as cursor
    }
    if (b == 0 && t == 0) rowptr[N_NODES] = N_EDGES;
    __syncthreads();
    for (int i = beg + t; i < end; i += 256) {
        unsigned int p = pairs[i];
        int pos = atomicAdd(&h[p & 127u], 1);
        adjl[pos] = (int)(p >> 7);
    }
    __syncthreads();
    for (int i = t; i < n; i += 256) adj[beg + i] = adjl[i];
}

// Wt[j][k] = bf16(W[k][j])
__global__ __launch_bounds__(256) void k_prep(const float* __restrict__ W,
                                              unsigned short* __restrict__ Wt) {
    int tid = blockIdx.x * 256 + threadIdx.x;   // 64 x 256 = 16384
    int k = tid & 127;
    int j = tid >> 7;
    Wt[j * 128 + k] = f2bf(W[k * 128 + j]);
}

// hs[r][:] = bf16( (x[r][:] @ W) * dis[r] ), MFMA 16x16x32 bf16.
__global__ __launch_bounds__(128) void k_gemm(const float* __restrict__ x,
                                              const unsigned short* __restrict__ Wt,
                                              const float* __restrict__ dis,
                                              unsigned short* __restrict__ hs) {
    __shared__ __align__(16) unsigned short wlds[128 * 128];  // 32 KiB, XOR-swizzled
    __shared__ __align__(16) unsigned short xlds[BM * 136];   // padded rows

    const int t = threadIdx.x;
    {
        const ulonglong2* srcp = (const ulonglong2*)Wt;
#pragma unroll
        for (int i = 0; i < 16; ++i) {
            int c = i * 128 + t;
            int byte = c << 4;
            int row = byte >> 8;
            int dstb = byte ^ ((row & 7) << 4);
            *(ulonglong2*)((char*)wlds + dstb) = srcp[c];
        }
    }
    const int row0 = blockIdx.x * BM;
    {
        const float4* xs4 = (const float4*)(x + (size_t)row0 * C);
#pragma unroll
        for (int i = 0; i < 8; ++i) {
            int c = i * 128 + t;
            float4 v = xs4[c];
            int row = c >> 5;
            int k4  = (c & 31) << 2;
            unsigned long long pk =
                  (unsigned long long)f2bf(v.x)
                | ((unsigned long long)f2bf(v.y) << 16)
                | ((unsigned long long)f2bf(v.z) << 32)
                | ((unsigned long long)f2bf(v.w) << 48);
            *(unsigned long long*)&xlds[row * 136 + k4] = pk;
        }
    }
    __syncthreads();

    const int wv   = t >> 6;
    const int lane = t & 63;
    const int m    = lane & 15;
    const int kg   = lane >> 4;

    f32x4 acc[8] = {};
#pragma unroll
    for (int s = 0; s < 4; ++s) {
        const int k = s * 32 + kg * 8;
        s16x8 a = *(const s16x8*)&xlds[(wv * 16 + m) * 136 + k];
#pragma unroll
        for (int j0 = 0; j0 < 8; ++j0) {
            const int n = j0 * 16 + m;
            const int byte = n * 256 + k * 2;
            const int swz = byte ^ ((n & 7) << 4);
            s16x8 b = *(const s16x8*)((const char*)wlds + swz);
            acc[j0] = __builtin_amdgcn_mfma_f32_16x16x32_bf16(a, b, acc[j0], 0, 0, 0);
        }
    }

#pragma unroll
    for (int reg = 0; reg < 4; ++reg) {
        const int r = row0 + wv * 16 + kg * 4 + reg;
        const float sd = dis[r];
#pragma unroll
        for (int j0 = 0; j0 < 8; ++j0) {
            hs[(size_t)r * C + j0 * 16 + m] = f2bf(acc[j0][reg] * sd);
        }
    }
}

// one wave per node; TWO edges in flight per wave: lanes 0-31 edge j (8B each),
// lanes 32-63 edge j+1. Cross-half shfl_xor reduce at the end. Fused epilogue.
__global__ __launch_bounds__(256) void k_gather(const int* __restrict__ rowptr,
                                                const int* __restrict__ adj,
                                                const unsigned long long* __restrict__ hs8,
                                                const float* __restrict__ dis,
                                                const float* __restrict__ b,
                                                const float* __restrict__ alpha,
                                                float* __restrict__ out) {
    const int d = (blockIdx.x * 256 + threadIdx.x) >> 6;
    const int lane = threadIdx.x & 63;
    if (d >= N_NODES) return;
    const int half = lane >> 5;     // 0: even edges, 1: odd edges
    const int c8   = lane & 31;     // 8B chunk = cols [4*c8, 4*c8+4)
    const int beg = rowptr[d], end = rowptr[d + 1];

    float a0 = 0.f, a1 = 0.f, a2 = 0.f, a3 = 0.f;
    if (half == 0) {   // self-loop term, added once
        unsigned long long u = hs8[(size_t)d * 32 + c8];
        unsigned int lo = (unsigned int)u, hi = (unsigned int)(u >> 32);
        a0 = __uint_as_float(lo << 16);
        a1 = __uint_as_float(lo & 0xffff0000u);
        a2 = __uint_as_float(hi << 16);
        a3 = __uint_as_float(hi & 0xffff0000u);
    }

    int jj = beg;
    for (; jj + 3 < end; jj += 4) {      // 4 edges per iter, 2 row-loads/lane in flight
        int s0 = adj[jj + half];
        int s1 = adj[jj + 2 + half];
        unsigned long long u0 = hs8[(size_t)s0 * 32 + c8];
        unsigned long long u1 = hs8[(size_t)s1 * 32 + c8];
        unsigned int lo0 = (unsigned int)u0, hi0 = (unsigned int)(u0 >> 32);
        unsigned int lo1 = (unsigned int)u1, hi1 = (unsigned int)(u1 >> 32);
        a0 += __uint_as_float(lo0 << 16);         a1 += __uint_as_float(lo0 & 0xffff0000u);
        a2 += __uint_as_float(hi0 << 16);         a3 += __uint_as_float(hi0 & 0xffff0000u);
        a0 += __uint_as_float(lo1 << 16);         a1 += __uint_as_float(lo1 & 0xffff0000u);
        a2 += __uint_as_float(hi1 << 16);         a3 += __uint_as_float(hi1 & 0xffff0000u);
    }
    {   // tail: up to 3 edges
        int e = jj + half;
        if (e < end) {
            unsigned long long u = hs8[(size_t)adj[e] * 32 + c8];
            unsigned int lo = (unsigned int)u, hi = (unsigned int)(u >> 32);
            a0 += __uint_as_float(lo << 16);      a1 += __uint_as_float(lo & 0xffff0000u);
            a2 += __uint_as_float(hi << 16);      a3 += __uint_as_float(hi & 0xffff0000u);
        }
        e += 2;
        if (e < end) {
            unsigned long long u = hs8[(size_t)adj[e] * 32 + c8];
            unsigned int lo = (unsigned int)u, hi = (unsigned int)(u >> 32);
            a0 += __uint_as_float(lo << 16);      a1 += __uint_as_float(lo & 0xffff0000u);
            a2 += __uint_as_float(hi << 16);      a3 += __uint_as_float(hi & 0xffff0000u);
        }
    }

    // combine halves (lane l <-> lane l^32 hold the same columns)
    a0 += __shfl_xor(a0, 32);
    a1 += __shfl_xor(a1, 32);
    a2 += __shfl_xor(a2, 32);
    a3 += __shfl_xor(a3, 32);

    if (half == 0) {
        const float sd = dis[d];
        const float al = alpha[0];
        float4 bv = *(const float4*)&b[c8 * 4];
        float t0 = fmaf(a0, sd, bv.x);
        float t1 = fmaf(a1, sd, bv.y);
        float t2 = fmaf(a2, sd, bv.z);
        float t3 = fmaf(a3, sd, bv.w);
        float4 r;
        r.x = t0 >= 0.f ? t0 : al * t0;
        r.y = t1 >= 0.f ? t1 : al * t1;
        r.z = t2 >= 0.f ? t2 : al * t2;
        r.w = t3 >= 0.f ? t3 : al * t3;
        *(float4*)&out[(size_t)d * C + c8 * 4] = r;
    }
}

extern "C" void kernel_launch(void* const* d_in, const int* in_sizes, int n_in,
                              void* d_out, int out_size, void* d_ws, size_t ws_size,
                              hipStream_t stream) {
    const float* x     = (const float*)d_in[0];
    const int*   ei    = (const int*)d_in[1];     // [2][E] flat: row0=src, row1=dst
    const float* W     = (const float*)d_in[2];
    const float* b     = (const float*)d_in[3];
    const float* alpha = (const float*)d_in[4];
    float* out = (float*)d_out;

    const int* src = ei;
    const int* dst = ei + N_EDGES;

    // workspace layout (hs ends up 16B-aligned: 13,642,160 bytes precede it)
    char* p = (char*)d_ws;
    int* bhist = (int*)p;                    p += sizeof(int) * NBUCK;
    int* bbase = (int*)p;                    p += sizeof(int) * (NBUCK + 1);
    int* gcur  = (int*)p;                    p += sizeof(int) * NBUCK;
    int* rowptr = (int*)p;                   p += sizeof(int) * (N_NODES + 1);
    float* dis = (float*)p;                  p += sizeof(float) * N_NODES;
    unsigned int* pairs = (unsigned int*)p;  p += sizeof(unsigned int) * N_EDGES;
    int* adj = (int*)p;                      p += sizeof(int) * N_EDGES;
    unsigned short* Wt = (unsigned short*)p; p += sizeof(unsigned short) * C * C;
    unsigned short* hs = (unsigned short*)p; // N*C bf16 (25.6 MB)

    k_zerob<<<1, 1024, 0, stream>>>(bhist);
    k_bhist<<<ABLKS, 256, 0, stream>>>(dst, bhist);
    k_bscan<<<1, 1024, 0, stream>>>(bhist, bbase, gcur);
    k_binscatter<<<ABLKS, 256, 0, stream>>>(src, dst, gcur, pairs);
    k_bucket<<<NBUCK, 256, 0, stream>>>(bbase, pairs, rowptr, dis, adj);
    k_prep<<<64, 256, 0, stream>>>(W, Wt);
    k_gemm<<<N_NODES / BM, 128, 0, stream>>>(x, Wt, dis, hs);
    k_gather<<<(N_NODES * 64 + 255) / 256, 256, 0, stream>>>(rowptr, adj,
                                                             (const unsigned long long*)hs,
                                                             dis, b, alpha, out);
}